// Round 11
// baseline (486.711 us; speedup 1.0000x reference)
//
#include <hip/hip_runtime.h>
#include <hip/hip_bf16.h>

#define DEV __device__ __forceinline__

typedef __attribute__((ext_vector_type(8))) short bf16x8;
typedef __attribute__((ext_vector_type(4))) float f32x4;

DEV float bf2f(short s){ unsigned u = ((unsigned)(unsigned short)s) << 16; return __builtin_bit_cast(float, u); }
DEV short f2bf(float f){ __hip_bfloat16 h = __float2bfloat16(f); return __builtin_bit_cast(short, h); }

// flag-dispatched loads from external float inputs (f=1: fp32, f=0: bf16)
DEV float ldf(const void* p, long i, int f){
  return f ? ((const float*)p)[i] : bf2f(((const short*)p)[i]);
}
DEV float4 ldf4(const void* p, long i, int f){   // i must be a multiple of 4
  if(f) return *(const float4*)((const float*)p + i);
  short4 v = *(const short4*)((const short*)p + i);
  return make_float4(bf2f(v.x), bf2f(v.y), bf2f(v.z), bf2f(v.w));
}

// Detect external float dtype: fp32 reinterpreted as bf16 shorts gives huge
// max over x_emb1's even shorts; genuine bf16 gives ~0.1.
__global__ void probe_k(const void* __restrict__ xe1, int nelem, int* __restrict__ flag){
  const short* p = (const short*)xe1;
  float m = 0.f;
  for(int i = threadIdx.x*2; i < nelem; i += 512){
    float v = fabsf(bf2f(p[i]));
    if(v > m) m = v;
  }
  for(int o = 32; o > 0; o >>= 1) m = fmaxf(m, __shfl_xor(m, o));
  __shared__ float sm[4];
  if((threadIdx.x & 63) == 0) sm[threadIdx.x >> 6] = m;
  __syncthreads();
  if(threadIdx.x == 0){
    float mm = fmaxf(fmaxf(sm[0], sm[1]), fmaxf(sm[2], sm[3]));
    flag[0] = (mm > 1000.f) ? 1 : 0;
  }
}

// origin_h -> catb[:, 0:128] (bf16)
__global__ void embed_k(const int* __restrict__ x, const void* __restrict__ e1,
                        const void* __restrict__ e2, const int* __restrict__ flagp,
                        short* __restrict__ catb, int N){
  int i = blockIdx.x*blockDim.x + threadIdx.x;
  if(i >= N*32) return;
  int f = *flagp;
  int n = i >> 5, d4 = (i & 31) << 2;
  int a = x[2*n], b = x[2*n+1];
  float4 v1 = ldf4(e1, a*128 + d4, f);
  float4 v2 = ldf4(e2, b*128 + d4, f);
  short4 o; o.x=f2bf(v1.x+v2.x); o.y=f2bf(v1.y+v2.y);
  o.z=f2bf(v1.z+v2.z); o.w=f2bf(v1.w+v2.w);
  *(short4*)(catb + (size_t)n*256 + d4) = o;
}

// ---------- CSR build (once; dst static across layers) ----------
__global__ void hist_k(const int* __restrict__ dst, int* __restrict__ deg, int E){
  int e = blockIdx.x*blockDim.x + threadIdx.x;
  if(e < E) atomicAdd(&deg[dst[e]], 1);
}
__global__ void scanA_k(const int* __restrict__ deg, int* __restrict__ bsum,
                        int M, int chunk, int ept){
  __shared__ int sm[256];
  int lo = blockIdx.x*chunk;
  int a = lo + threadIdx.x*ept, b = min(min(M, lo+chunk), a+ept);
  int s = 0;
  for(int i = a; i < b; i++) s += deg[i];
  sm[threadIdx.x] = s; __syncthreads();
  for(int o = 128; o > 0; o >>= 1){
    if(threadIdx.x < o) sm[threadIdx.x] += sm[threadIdx.x+o];
    __syncthreads();
  }
  if(threadIdx.x == 0) bsum[blockIdx.x] = sm[0];
}
__global__ void scanB_k(const int* __restrict__ bsum, int* __restrict__ boff, int nb){
  __shared__ int sm[256];
  int t = threadIdx.x;
  int v = (t < nb) ? bsum[t] : 0;
  sm[t] = v; __syncthreads();
  for(int o = 1; o < 256; o <<= 1){
    int u = (t >= o) ? sm[t-o] : 0; __syncthreads();
    sm[t] += u; __syncthreads();
  }
  if(t < nb) boff[t] = sm[t] - v;   // exclusive
}
__global__ void scanC_k(const int* __restrict__ deg, const int* __restrict__ boff,
                        int* __restrict__ rowptr, int M, int chunk, int ept, int E){
  __shared__ int sm[256];
  int lo = blockIdx.x*chunk;
  int a = lo + threadIdx.x*ept, b = min(min(M, lo+chunk), a+ept);
  int s = 0;
  for(int i = a; i < b; i++) s += deg[i];
  int v = s;
  sm[threadIdx.x] = v; __syncthreads();
  for(int o = 1; o < 256; o <<= 1){
    int u = (threadIdx.x >= o) ? sm[threadIdx.x-o] : 0; __syncthreads();
    sm[threadIdx.x] += u; __syncthreads();
  }
  int base = boff[blockIdx.x] + sm[threadIdx.x] - v;
  for(int i = a; i < b; i++){ rowptr[i] = base; base += deg[i]; }
  if(blockIdx.x == 0 && threadIdx.x == 0) rowptr[M] = E;
}
// payloads: pl1[pos] = src | (attr_idx<<18)        (h-space, layer 1)
//           pl0[pos] = sgn[src] | (attr_idx<<18)   (catb-space, layer 0)
__global__ void fill_k(const int* __restrict__ src, const int* __restrict__ dst,
                       const int* __restrict__ attr, const int* __restrict__ sgn,
                       int* __restrict__ cursor,
                       unsigned* __restrict__ pl0, unsigned* __restrict__ pl1, int E){
  int e = blockIdx.x*blockDim.x + threadIdx.x;
  if(e >= E) return;
  int t = dst[e];
  int pos = atomicAdd(&cursor[t], 1);
  unsigned idx = (unsigned)(attr[2*e]*3 + attr[2*e+1]);
  int s = src[e];
  pl1[pos] = (unsigned)s | (idx << 18);
  pl0[pos] = (unsigned)sgn[s] | (idx << 18);
}

// per-layer edge-embedding table: rows 0..8 = ee1[a0]+ee2[a1], row 9 = selfloop
__global__ void eet_k(const void* __restrict__ ee1, const void* __restrict__ ee2,
                      int o1, int o2, const int* __restrict__ flagp,
                      float* __restrict__ eet){
  int i = blockIdx.x*blockDim.x + threadIdx.x;
  if(i >= 10*128) return;
  int f = *flagp;
  int r = i >> 7, d = i & 127;
  float v;
  if(r == 9) v = ldf(ee1, o1 + 4*128 + d, f) + ldf(ee2, o2 + d, f);
  else       v = ldf(ee1, o1 + (r/3)*128 + d, f) + ldf(ee2, o2 + (r%3)*128 + d, f);
  eet[i] = v;
}

// dst[n][k] = bf16(src[soff + k*N + n]), dst rows padded to ld
__global__ void transpose_k(const void* __restrict__ src, long soff,
                            const int* __restrict__ flagp,
                            short* __restrict__ dst, int K, int N, int ld){
  int i = blockIdx.x*blockDim.x + threadIdx.x;
  if(i >= K*N) return;
  int f = *flagp;
  int k = i / N, n = i % N;
  float v = ldf(src, soff + i, f);
  dst[n*ld + k] = f2bf(v);
}

// ---------------- fused GIN layer: 32 rows, 128 threads, 17.4KB LDS ----------------
// HS = row stride of hin (256 for catb, 128 for h). selfidx: optional m->row map.
// Small blocks -> 8-9 blocks/CU resident -> latency-bound gather gets waves.
template<int HS>
__global__ __launch_bounds__(128, 4) void layer_k(
    const short* __restrict__ hin, const int* __restrict__ selfidx,
    const int* __restrict__ rowptr, const unsigned* __restrict__ pl,
    const float* __restrict__ eet,
    const short* __restrict__ w1t, const short* __restrict__ w2t,
    const void* __restrict__ b1, long boff1,
    const void* __restrict__ b2, long boff2,
    const int* __restrict__ flagp, short* __restrict__ hout, int M){
  __shared__ alignas(16) short agg_s[32*136];   // 272B stride: 2-way banks (free)
  __shared__ alignas(16) short hid_s[32*136];   // one 128-col half of hidden
  const int f = *flagp;
  const int rowbase = blockIdx.x*32;

  // ---- phase 0: gather-aggregate (fp32 accum, bf16 store) ----
  {
    const int rl = threadIdx.x >> 5;          // 0..3 (row group)
    const int d4 = (threadIdx.x & 31) << 2;
    const float4 sl = *(const float4*)(eet + 9*128 + d4);
#pragma unroll 1
    for(int r8 = 0; r8 < 8; r8++){
      int rloc = r8*4 + rl;
      int m = rowbase + rloc; if(m >= M) m = M-1;
      int self = selfidx ? selfidx[m] : m;
      short4 hv = *(const short4*)(hin + (size_t)self*HS + d4);
      float4 acc = make_float4(bf2f(hv.x)+sl.x, bf2f(hv.y)+sl.y,
                               bf2f(hv.z)+sl.z, bf2f(hv.w)+sl.w);
      int r0 = rowptr[m], r1 = rowptr[m+1];
      for(int j = r0; j < r1; j++){
        unsigned p = pl[j];
        int s = p & 0x3FFFF, idx = p >> 18;
        short4 hs = *(const short4*)(hin + (size_t)s*HS + d4);
        float4 ee = *(const float4*)(eet + idx*128 + d4);
        acc.x += bf2f(hs.x)+ee.x; acc.y += bf2f(hs.y)+ee.y;
        acc.z += bf2f(hs.z)+ee.z; acc.w += bf2f(hs.w)+ee.w;
      }
      short4 o; o.x=f2bf(acc.x); o.y=f2bf(acc.y); o.z=f2bf(acc.z); o.w=f2bf(acc.w);
      *(short4*)(agg_s + rloc*136 + d4) = o;
    }
  }
  __syncthreads();

  const int lane = threadIdx.x & 63, wave = threadIdx.x >> 6;   // wave 0..1
  const int l16 = lane & 15, lq = lane >> 4;

  f32x4 acc2[2][4] = {};
#pragma unroll 1
  for(int half = 0; half < 2; half++){
    if(half) __syncthreads();   // protect hid_s from previous-half readers

    // ---- phase 1: hidden half = relu(agg @ W1[:, half*128+wave*64+...] + b1) ----
    f32x4 acc1[2][4] = {};
#pragma unroll
    for(int ks = 0; ks < 4; ks++){
      const int k0 = ks*32 + lq*8;
      bf16x8 a[2];
#pragma unroll
      for(int rt = 0; rt < 2; rt++)
        a[rt] = *(const bf16x8*)(agg_s + (rt*16 + l16)*136 + k0);
#pragma unroll
      for(int ct = 0; ct < 4; ct++){
        const int ch = half*128 + wave*64 + ct*16 + l16;   // global hidden col
        bf16x8 b = *(const bf16x8*)(w1t + ch*136 + k0);
#pragma unroll
        for(int rt = 0; rt < 2; rt++)
          acc1[rt][ct] = __builtin_amdgcn_mfma_f32_16x16x32_bf16(a[rt], b, acc1[rt][ct], 0, 0, 0);
      }
    }
#pragma unroll
    for(int ct = 0; ct < 4; ct++){
      const int ch = half*128 + wave*64 + ct*16 + l16;
      const int cl = wave*64 + ct*16 + l16;                // local col in hid_s
      const float bs = ldf(b1, boff1 + ch, f);
#pragma unroll
      for(int rt = 0; rt < 2; rt++){
#pragma unroll
        for(int i2 = 0; i2 < 4; i2++){
          float v = fmaxf(acc1[rt][ct][i2] + bs, 0.f);
          hid_s[(rt*16 + lq*4 + i2)*136 + cl] = f2bf(v);
        }
      }
    }
    __syncthreads();

    // ---- phase 2: acc2 += hidden_half @ W2[half*128.., :] ----
#pragma unroll
    for(int ks = 0; ks < 4; ks++){
      const int kl = ks*32 + lq*8;            // local k in hid_s
      const int kg = half*128 + kl;           // global k for w2t
      bf16x8 a[2];
#pragma unroll
      for(int rt = 0; rt < 2; rt++)
        a[rt] = *(const bf16x8*)(hid_s + (rt*16 + l16)*136 + kl);
#pragma unroll
      for(int ct = 0; ct < 4; ct++){
        const int col = wave*64 + ct*16 + l16;
        bf16x8 b = *(const bf16x8*)(w2t + col*264 + kg);
#pragma unroll
        for(int rt = 0; rt < 2; rt++)
          acc2[rt][ct] = __builtin_amdgcn_mfma_f32_16x16x32_bf16(a[rt], b, acc2[rt][ct], 0, 0, 0);
      }
    }
  }

  // ---- epilogue ----
#pragma unroll
  for(int ct = 0; ct < 4; ct++){
    const int col = wave*64 + ct*16 + l16;
    const float bs = ldf(b2, boff2 + col, f);
#pragma unroll
    for(int rt = 0; rt < 2; rt++){
#pragma unroll
      for(int i2 = 0; i2 < 4; i2++){
        int row = rowbase + rt*16 + lq*4 + i2;
        if(row < M){
          float v = fmaxf(acc2[rt][ct][i2] + bs, 0.f);
          hout[(size_t)row*128 + col] = f2bf(v);
        }
      }
    }
  }
}

// x_struct: catb[n][128+d] = sum over m with ind[m]==n of h[m][d]; ind sorted
DEV int lower_bound_i(const int* a, int len, int v){
  int lo = 0, hi = len;
  while(lo < hi){ int mid = (lo+hi) >> 1; if(a[mid] < v) lo = mid+1; else hi = mid; }
  return lo;
}
__global__ void xstruct_k(const short* __restrict__ h, const int* __restrict__ ind,
                          short* __restrict__ catb, int M, int N){
  int n = blockIdx.x*8 + (threadIdx.x >> 5);
  if(n >= N) return;
  int d4 = (threadIdx.x & 31) << 2;
  int l0 = lower_bound_i(ind, M, n);
  int l1 = lower_bound_i(ind, M, n+1);
  float4 acc = make_float4(0.f, 0.f, 0.f, 0.f);
  for(int m = l0; m < l1; m++){
    short4 hv = *(const short4*)(h + (size_t)m*128 + d4);
    acc.x += bf2f(hv.x); acc.y += bf2f(hv.y);
    acc.z += bf2f(hv.z); acc.w += bf2f(hv.w);
  }
  short4 o; o.x=f2bf(acc.x); o.y=f2bf(acc.y); o.z=f2bf(acc.z); o.w=f2bf(acc.w);
  *(short4*)(catb + (size_t)n*256 + 128 + d4) = o;
}

// ---- BN stats, stage 1: 256 blocks, vectorized, LDS-reduced, atomic finish ----
template<int COLS, bool BF>
__global__ __launch_bounds__(256) void bnstats1_k(const void* __restrict__ buf,
                          float* __restrict__ stats, int rows){
  constexpr int CG = COLS/4;        // col-groups of 4
  constexpr int RP = 256/CG;        // row-slices per block
  const int cg = threadIdx.x % CG, rs = threadIdx.x / CG;
  const int c4 = cg*4;
  float4 s = make_float4(0,0,0,0), q = make_float4(0,0,0,0);
  for(int r = blockIdx.x*RP + rs; r < rows; r += gridDim.x*RP){
    float4 v;
    if(BF){
      short4 sv = *(const short4*)((const short*)buf + (size_t)r*COLS + c4);
      v = make_float4(bf2f(sv.x), bf2f(sv.y), bf2f(sv.z), bf2f(sv.w));
    } else {
      v = *(const float4*)((const float*)buf + (size_t)r*COLS + c4);
    }
    s.x += v.x; s.y += v.y; s.z += v.z; s.w += v.w;
    q.x += v.x*v.x; q.y += v.y*v.y; q.z += v.z*v.z; q.w += v.w*v.w;
  }
  __shared__ float sm[256][8];
  sm[threadIdx.x][0]=s.x; sm[threadIdx.x][1]=s.y; sm[threadIdx.x][2]=s.z; sm[threadIdx.x][3]=s.w;
  sm[threadIdx.x][4]=q.x; sm[threadIdx.x][5]=q.y; sm[threadIdx.x][6]=q.z; sm[threadIdx.x][7]=q.w;
  __syncthreads();
  if(rs == 0){
    float acc[8];
#pragma unroll
    for(int j = 0; j < 8; j++) acc[j] = sm[cg][j];
    for(int j = 1; j < RP; j++)
#pragma unroll
      for(int t = 0; t < 8; t++) acc[t] += sm[j*CG + cg][t];
#pragma unroll
    for(int t = 0; t < 4; t++) atomicAdd(&stats[c4+t], acc[t]);
#pragma unroll
    for(int t = 0; t < 4; t++) atomicAdd(&stats[COLS + c4+t], acc[4+t]);
  }
}

__global__ void bnfin_k(const float* __restrict__ stats, const void* __restrict__ gamma,
                        const void* __restrict__ beta, const int* __restrict__ flagp,
                        float* __restrict__ scl, float* __restrict__ sft,
                        int cols, float invN){
  int c = threadIdx.x; if(c >= cols) return;
  int f = *flagp;
  float mean = stats[c]*invN;
  float var  = stats[cols+c]*invN - mean*mean;
  float s = ldf(gamma, c, f) * rsqrtf(var + 1e-5f);
  scl[c] = s; sft[c] = ldf(beta, c, f) - mean*s;
}

// out = BN2(out2) stored per output dtype flag
__global__ void bn2apply_k(const float* __restrict__ out2, const float* __restrict__ scl,
                           const float* __restrict__ sft, const int* __restrict__ flagp,
                           void* __restrict__ outv, int N){
  int i = blockIdx.x*blockDim.x + threadIdx.x;
  if(i >= N*32) return;
  int f = *flagp;
  int n = i >> 5, d4 = (i & 31) << 2;
  size_t idx = (size_t)n*128 + d4;
  float4 v = *(const float4*)(out2 + idx);
  float4 o = make_float4(v.x*scl[d4+0] + sft[d4+0], v.y*scl[d4+1] + sft[d4+1],
                         v.z*scl[d4+2] + sft[d4+2], v.w*scl[d4+3] + sft[d4+3]);
  if(f){
    *(float4*)((float*)outv + idx) = o;
  } else {
    short4 s; s.x=f2bf(o.x); s.y=f2bf(o.y); s.z=f2bf(o.z); s.w=f2bf(o.w);
    *(short4*)((short*)outv + idx) = s;
  }
}

// ---------------- MFMA GEMM (projection only) ----------------
template<int KK, int NN, int AMODE, bool RELU, bool OFLOAT>
__global__ __launch_bounds__(256) void gemm_k(const void* __restrict__ Av,
        const short* __restrict__ BT, const void* __restrict__ bias, long boff,
        const int* __restrict__ flagp,
        const float* __restrict__ scl, const float* __restrict__ sft,
        void* __restrict__ Ov, int Mrows){
  constexpr int CT  = NN/64;
  constexpr int KS  = KK/32;
  constexpr int LDB = KK + 8;
  __shared__ alignas(16) short bt[NN*LDB];
  {
    const float4* s = (const float4*)BT;
    float4* d = (float4*)bt;
    constexpr int total = NN*LDB*2/16;
    for(int i = threadIdx.x; i < total; i += 256) d[i] = s[i];
  }
  const int f = *flagp;
  __syncthreads();

  const int lane = threadIdx.x & 63, wave = threadIdx.x >> 6;
  const int l16 = lane & 15, lq = lane >> 4;
  const int rowbase = blockIdx.x * 64;
  const int colbase = wave * (NN/4);

  f32x4 acc[4][CT] = {};
  for(int ks = 0; ks < KS; ks++){
    const int k0 = ks*32 + lq*8;
    bf16x8 a[4];
#pragma unroll
    for(int rt = 0; rt < 4; rt++){
      int row = rowbase + rt*16 + l16;
      if(row >= Mrows) row = Mrows - 1;
      bf16x8 av = *(const bf16x8*)((const short*)Av + (size_t)row*KK + k0);
      if constexpr (AMODE == 2){
        bf16x8 aw;
#pragma unroll
        for(int j = 0; j < 8; j++) aw[j] = f2bf(bf2f(av[j])*scl[k0+j] + sft[k0+j]);
        a[rt] = aw;
      } else {
        a[rt] = av;
      }
    }
#pragma unroll
    for(int ct = 0; ct < CT; ct++){
      bf16x8 b = *(const bf16x8*)(bt + (colbase + ct*16 + l16)*LDB + k0);
#pragma unroll
      for(int rt = 0; rt < 4; rt++)
        acc[rt][ct] = __builtin_amdgcn_mfma_f32_16x16x32_bf16(a[rt], b, acc[rt][ct], 0, 0, 0);
    }
  }
#pragma unroll
  for(int ct = 0; ct < CT; ct++){
    const int col = colbase + ct*16 + l16;
    const float bs = ldf(bias, boff + col, f);
#pragma unroll
    for(int rt = 0; rt < 4; rt++){
#pragma unroll
      for(int i2 = 0; i2 < 4; i2++){
        int row = rowbase + rt*16 + lq*4 + i2;
        if(row < Mrows){
          float v = acc[rt][ct][i2] + bs;
          if constexpr (RELU) v = fmaxf(v, 0.f);
          if constexpr (OFLOAT) ((float*)Ov)[(size_t)row*NN + col] = v;
          else ((short*)Ov)[(size_t)row*NN + col] = f2bf(v);
        }
      }
    }
  }
}

extern "C" void kernel_launch(void* const* d_in, const int* in_sizes, int n_in,
                              void* d_out, int out_size, void* d_ws, size_t ws_size,
                              hipStream_t stream){
  const int*  x    = (const int*)d_in[0];
  const int*  sgn  = (const int*)d_in[3];
  const int*  sge  = (const int*)d_in[4];
  const int*  sga  = (const int*)d_in[5];
  const int*  sgi  = (const int*)d_in[6];
  const void* xe1  = d_in[7];
  const void* xe2  = d_in[8];
  const void* ee1  = d_in[9];   // [2][6][128]
  const void* ee2  = d_in[10];  // [2][3][128]
  const void* W1   = d_in[11];  // [2][128][256]
  const void* b1   = d_in[12];  // [2][256]
  const void* W2   = d_in[13];  // [2][256][128]
  const void* b2   = d_in[14];  // [2][128]
  const void* g1   = d_in[15];
  const void* be1  = d_in[16];
  const void* Wp   = d_in[17];  // [256][128]
  const void* bp   = d_in[18];
  const void* g2   = d_in[19];
  const void* be2  = d_in[20];

  const int N = in_sizes[0] / 2;     // 20000
  const int M = in_sizes[3];         // 200000
  const int E = in_sizes[4] / 2;     // 400000
  const int* esrc = sge;
  const int* edst = sge + E;

  size_t off = 0;
  auto alloc = [&](size_t bytes)->void*{
    void* p = (char*)d_ws + off;
    off += (bytes + 255) & ~(size_t)255;
    return p;
  };
  int*      flag   = (int*)alloc(4);
  short*    catb   = (short*)alloc((size_t)N*256*2);   // bf16 [N][256]: [orig | x_struct]
  short*    ha     = (short*)alloc((size_t)M*128*2);   // h ping
  short*    hb     = (short*)alloc((size_t)M*128*2);   // h pong (also out2 alias)
  short*    w1t    = (short*)alloc((size_t)2*256*136*2);
  short*    w2t    = (short*)alloc((size_t)2*128*264*2);
  short*    wpt    = (short*)alloc((size_t)128*264*2);
  float*    stats  = (float*)alloc((size_t)(512+256)*4);
  float*    scl1   = (float*)alloc(256*4);
  float*    sft1   = (float*)alloc(256*4);
  float*    scl2   = (float*)alloc(128*4);
  float*    sft2   = (float*)alloc(128*4);
  int*      rowptr = (int*)alloc((size_t)(M+1)*4);
  int*      degcur = (int*)alloc((size_t)M*4);         // deg, then cursor
  unsigned* pl0    = (unsigned*)alloc((size_t)E*4);    // catb-space payload
  unsigned* pl1    = (unsigned*)alloc((size_t)E*4);    // h-space payload
  int*      bsum   = (int*)alloc(256*4);
  int*      boff   = (int*)alloc(256*4);
  float*    eet    = (float*)alloc((size_t)2*10*128*4);
  float*    out2   = (float*)hb;    // hb dead after layer1 (hb -> ha)

  if(off > ws_size) return;

  const int NB = 240;
  const int chunk = (M + NB - 1) / NB;
  const int ept = (chunk + 255) / 256;

  (void)hipMemsetAsync(stats, 0, (512+256)*4, stream);
  (void)hipMemsetAsync(degcur, 0, (size_t)M*4, stream);

  probe_k<<<1, 256, 0, stream>>>(xe1, 120*128, flag);

  // CSR build (edges static across layers)
  hist_k<<<(E+255)/256, 256, 0, stream>>>(edst, degcur, E);
  scanA_k<<<NB, 256, 0, stream>>>(degcur, bsum, M, chunk, ept);
  scanB_k<<<1, 256, 0, stream>>>(bsum, boff, NB);
  scanC_k<<<NB, 256, 0, stream>>>(degcur, boff, rowptr, M, chunk, ept, E);
  (void)hipMemcpyAsync(degcur, rowptr, (size_t)M*4, hipMemcpyDeviceToDevice, stream);
  fill_k<<<(E+255)/256, 256, 0, stream>>>(esrc, edst, sga, sgn, degcur, pl0, pl1, E);

  // per-layer constant prep (weights transposed, edge-emb tables)
  for(int l = 0; l < 2; l++){
    eet_k<<<5, 256, 0, stream>>>(ee1, ee2, l*6*128, l*3*128, flag, eet + l*1280);
    transpose_k<<<(128*256+255)/256, 256, 0, stream>>>(W1, (long)l*128*256, flag,
        w1t + (size_t)l*256*136, 128, 256, 136);
    transpose_k<<<(256*128+255)/256, 256, 0, stream>>>(W2, (long)l*256*128, flag,
        w2t + (size_t)l*128*264, 256, 128, 264);
  }

  embed_k<<<(N*32+255)/256, 256, 0, stream>>>(x, xe1, xe2, flag, catb, N);

  // fused GIN layers: catb --(gather folded)--> hb -> ha
  layer_k<256><<<(M+31)/32, 128, 0, stream>>>(catb, sgn, rowptr, pl0, eet,
      w1t, w2t, b1, 0, b2, 0, flag, hb, M);
  layer_k<128><<<(M+31)/32, 128, 0, stream>>>(hb, nullptr, rowptr, pl1, eet + 1280,
      w1t + (size_t)256*136, w2t + (size_t)128*264, b1, 256, b2, 128, flag, ha, M);

  xstruct_k<<<(N+7)/8, 256, 0, stream>>>(ha, sgi, catb, M, N);

  bnstats1_k<256,true><<<256, 256, 0, stream>>>(catb, stats, N);
  bnfin_k<<<1, 256, 0, stream>>>(stats, g1, be1, flag, scl1, sft1, 256, 1.0f/N);

  transpose_k<<<(256*128+255)/256, 256, 0, stream>>>(Wp, 0, flag, wpt, 256, 128, 264);
  gemm_k<256,128,2,false,true><<<(N+63)/64, 256, 0, stream>>>(
      catb, wpt, bp, 0, flag, scl1, sft1, out2, N);

  bnstats1_k<128,false><<<256, 256, 0, stream>>>(out2, stats + 512, N);
  bnfin_k<<<1, 128, 0, stream>>>(stats + 512, g2, be2, flag, scl2, sft2, 128, 1.0f/N);

  bn2apply_k<<<(N*32+255)/256, 256, 0, stream>>>(out2, scl2, sft2, flag, d_out, N);
}

// Round 12
// 479.405 us; speedup vs baseline: 1.0152x; 1.0152x over previous
//
#include <hip/hip_runtime.h>
#include <hip/hip_bf16.h>

#define DEV __device__ __forceinline__

typedef __attribute__((ext_vector_type(8))) short bf16x8;
typedef __attribute__((ext_vector_type(4))) float f32x4;

DEV float bf2f(short s){ unsigned u = ((unsigned)(unsigned short)s) << 16; return __builtin_bit_cast(float, u); }
DEV short f2bf(float f){ __hip_bfloat16 h = __float2bfloat16(f); return __builtin_bit_cast(short, h); }

// flag-dispatched loads from external float inputs (f=1: fp32, f=0: bf16)
DEV float ldf(const void* p, long i, int f){
  return f ? ((const float*)p)[i] : bf2f(((const short*)p)[i]);
}
DEV float4 ldf4(const void* p, long i, int f){   // i must be a multiple of 4
  if(f) return *(const float4*)((const float*)p + i);
  short4 v = *(const short4*)((const short*)p + i);
  return make_float4(bf2f(v.x), bf2f(v.y), bf2f(v.z), bf2f(v.w));
}

// Detect external float dtype: fp32 reinterpreted as bf16 shorts gives huge
// max over x_emb1's even shorts; genuine bf16 gives ~0.1.
__global__ void probe_k(const void* __restrict__ xe1, int nelem, int* __restrict__ flag){
  const short* p = (const short*)xe1;
  float m = 0.f;
  for(int i = threadIdx.x*2; i < nelem; i += 512){
    float v = fabsf(bf2f(p[i]));
    if(v > m) m = v;
  }
  for(int o = 32; o > 0; o >>= 1) m = fmaxf(m, __shfl_xor(m, o));
  __shared__ float sm[4];
  if((threadIdx.x & 63) == 0) sm[threadIdx.x >> 6] = m;
  __syncthreads();
  if(threadIdx.x == 0){
    float mm = fmaxf(fmaxf(sm[0], sm[1]), fmaxf(sm[2], sm[3]));
    flag[0] = (mm > 1000.f) ? 1 : 0;
  }
}

// ---- one-shot prep: eet tables (both layers) + w1t/w2t/wpt transposes ----
__global__ void prep_k(const void* __restrict__ ee1, const void* __restrict__ ee2,
                       const void* __restrict__ W1, const void* __restrict__ W2,
                       const void* __restrict__ Wp, const int* __restrict__ flagp,
                       float* __restrict__ eet, short* __restrict__ w1t,
                       short* __restrict__ w2t, short* __restrict__ wpt){
  const int f = *flagp;
  int i = blockIdx.x*blockDim.x + threadIdx.x;
  if(i < 2560){                                  // eet: [2][10][128]
    int l = i / 1280, j = i % 1280, r = j >> 7, d = j & 127;
    int o1 = l*768, o2 = l*384;
    float v;
    if(r == 9) v = ldf(ee1, o1 + 4*128 + d, f) + ldf(ee2, o2 + d, f);
    else       v = ldf(ee1, o1 + (r/3)*128 + d, f) + ldf(ee2, o2 + (r%3)*128 + d, f);
    eet[l*1280 + r*128 + d] = v;
  } else if(i < 2560 + 65536){                   // w1t: [2] 128x256 -> [256][136]
    int j = i - 2560; int l = j >> 15; j &= 32767;
    int k = j >> 8, n = j & 255;
    w1t[(size_t)l*256*136 + n*136 + k] = f2bf(ldf(W1, (long)l*32768 + j, f));
  } else if(i < 2560 + 131072){                  // w2t: [2] 256x128 -> [128][264]
    int j = i - 2560 - 65536; int l = j >> 15; j &= 32767;
    int k = j >> 7, n = j & 127;
    w2t[(size_t)l*128*264 + n*264 + k] = f2bf(ldf(W2, (long)l*32768 + j, f));
  } else if(i < 2560 + 131072 + 32768){          // wpt: 256x128 -> [128][264]
    int j = i - 2560 - 131072;
    int k = j >> 7, n = j & 127;
    wpt[n*264 + k] = f2bf(ldf(Wp, (long)j, f));
  }
}

// origin_h -> catb[:, 0:128] (bf16) + BN1 stats for cols 0..127
__global__ __launch_bounds__(256) void embed_k(const int* __restrict__ x,
                        const void* __restrict__ e1, const void* __restrict__ e2,
                        const int* __restrict__ flagp, short* __restrict__ catb,
                        float* __restrict__ stats, int N){
  const int f = *flagp;
  const int nl = threadIdx.x >> 5, d4 = (threadIdx.x & 31) << 2;
  float4 s = make_float4(0,0,0,0), q = make_float4(0,0,0,0);
  for(int n = blockIdx.x*8 + nl; n < N; n += gridDim.x*8){
    int a = x[2*n], b = x[2*n+1];
    float4 v1 = ldf4(e1, a*128 + d4, f);
    float4 v2 = ldf4(e2, b*128 + d4, f);
    short4 o; o.x=f2bf(v1.x+v2.x); o.y=f2bf(v1.y+v2.y);
    o.z=f2bf(v1.z+v2.z); o.w=f2bf(v1.w+v2.w);
    *(short4*)(catb + (size_t)n*256 + d4) = o;
    float4 fo = make_float4(bf2f(o.x), bf2f(o.y), bf2f(o.z), bf2f(o.w));
    s.x += fo.x; s.y += fo.y; s.z += fo.z; s.w += fo.w;
    q.x += fo.x*fo.x; q.y += fo.y*fo.y; q.z += fo.z*fo.z; q.w += fo.w*fo.w;
  }
  __shared__ float sm[256][8];
  sm[threadIdx.x][0]=s.x; sm[threadIdx.x][1]=s.y; sm[threadIdx.x][2]=s.z; sm[threadIdx.x][3]=s.w;
  sm[threadIdx.x][4]=q.x; sm[threadIdx.x][5]=q.y; sm[threadIdx.x][6]=q.z; sm[threadIdx.x][7]=q.w;
  __syncthreads();
  if(threadIdx.x < 32){
    int c4 = threadIdx.x << 2;
    float acc[8];
#pragma unroll
    for(int j = 0; j < 8; j++) acc[j] = sm[threadIdx.x][j];
    for(int g = 1; g < 8; g++)
#pragma unroll
      for(int j = 0; j < 8; j++) acc[j] += sm[g*32 + threadIdx.x][j];
#pragma unroll
    for(int t = 0; t < 4; t++) atomicAdd(&stats[c4+t], acc[t]);
#pragma unroll
    for(int t = 0; t < 4; t++) atomicAdd(&stats[256 + c4+t], acc[4+t]);
  }
}

// ---------- CSR build (once; dst static across layers) ----------
__global__ void hist_k(const int* __restrict__ dst, int* __restrict__ deg, int E){
  int e = blockIdx.x*blockDim.x + threadIdx.x;
  if(e < E) atomicAdd(&deg[dst[e]], 1);
}
__global__ void scanA_k(const int* __restrict__ deg, int* __restrict__ bsum,
                        int M, int chunk, int ept){
  __shared__ int sm[256];
  int lo = blockIdx.x*chunk;
  int a = lo + threadIdx.x*ept, b = min(min(M, lo+chunk), a+ept);
  int s = 0;
  for(int i = a; i < b; i++) s += deg[i];
  sm[threadIdx.x] = s; __syncthreads();
  for(int o = 128; o > 0; o >>= 1){
    if(threadIdx.x < o) sm[threadIdx.x] += sm[threadIdx.x+o];
    __syncthreads();
  }
  if(threadIdx.x == 0) bsum[blockIdx.x] = sm[0];
}
// scanC: per-block prefix from bsum (inline, replaces scanB) + rowptr + cursor
__global__ void scanC_k(const int* __restrict__ deg, const int* __restrict__ bsum,
                        int* __restrict__ rowptr, int* __restrict__ cursor,
                        int M, int chunk, int ept, int E){
  __shared__ int sm[256];
  const int t = threadIdx.x;
  sm[t] = (t < blockIdx.x) ? bsum[t] : 0;
  __syncthreads();
  for(int o = 128; o > 0; o >>= 1){
    if(t < o) sm[t] += sm[t+o];
    __syncthreads();
  }
  const int bpre = sm[0];
  __syncthreads();
  int lo = blockIdx.x*chunk;
  int a = lo + t*ept, b = min(min(M, lo+chunk), a+ept);
  int s = 0;
  for(int i = a; i < b; i++) s += deg[i];
  int v = s;
  sm[t] = v; __syncthreads();
  for(int o = 1; o < 256; o <<= 1){
    int u = (t >= o) ? sm[t-o] : 0; __syncthreads();
    sm[t] += u; __syncthreads();
  }
  int base = bpre + sm[t] - v;
  for(int i = a; i < b; i++){
    int d = deg[i];                 // read BEFORE cursor write (may alias deg)
    rowptr[i] = base; cursor[i] = base; base += d;
  }
  if(blockIdx.x == 0 && t == 0) rowptr[M] = E;
}
// payloads: pl1[pos] = src | (attr_idx<<18)        (h-space, layer 1)
//           pl0[pos] = sgn[src] | (attr_idx<<18)   (catb-space, layer 0)
__global__ void fill_k(const int* __restrict__ src, const int* __restrict__ dst,
                       const int* __restrict__ attr, const int* __restrict__ sgn,
                       int* __restrict__ cursor,
                       unsigned* __restrict__ pl0, unsigned* __restrict__ pl1, int E){
  int e = blockIdx.x*blockDim.x + threadIdx.x;
  if(e >= E) return;
  int t = dst[e];
  int pos = atomicAdd(&cursor[t], 1);
  unsigned idx = (unsigned)(attr[2*e]*3 + attr[2*e+1]);
  int s = src[e];
  pl1[pos] = (unsigned)s | (idx << 18);
  pl0[pos] = (unsigned)sgn[s] | (idx << 18);
}

// ---------------- fused GIN layer (round-9 config: 64 rows, 256t, 34.8KB) ----------------
// HS = row stride of hin (256 for catb, 128 for h). selfidx: optional m->row map.
template<int HS>
__global__ __launch_bounds__(256, 4) void layer_k(
    const short* __restrict__ hin, const int* __restrict__ selfidx,
    const int* __restrict__ rowptr, const unsigned* __restrict__ pl,
    const float* __restrict__ eet,
    const short* __restrict__ w1t, const short* __restrict__ w2t,
    const void* __restrict__ b1, long boff1,
    const void* __restrict__ b2, long boff2,
    const int* __restrict__ flagp, short* __restrict__ hout, int M){
  __shared__ alignas(16) short agg_s[64*136];   // 272B stride: 2-way banks (free)
  __shared__ alignas(16) short hid_s[64*136];   // one 128-col half of hidden
  const int f = *flagp;
  const int rowbase = blockIdx.x*64;

  // ---- phase 0: gather-aggregate, MLP-maximized ----
  {
    const int rl = threadIdx.x >> 5;          // 0..7 (row group)
    const int d4 = (threadIdx.x & 31) << 2;
    const float4 sl = *(const float4*)(eet + 9*128 + d4);
    int r0v[8], r1v[8];
    short4 hvv[8];
#pragma unroll
    for(int r8 = 0; r8 < 8; r8++){
      int m = rowbase + r8*8 + rl; if(m >= M) m = M-1;
      int self = selfidx ? selfidx[m] : m;
      hvv[r8] = *(const short4*)(hin + (size_t)self*HS + d4);
      r0v[r8] = rowptr[m];
      r1v[r8] = rowptr[m+1];
    }
#pragma unroll
    for(int r8 = 0; r8 < 8; r8++){
      float4 acc = make_float4(bf2f(hvv[r8].x)+sl.x, bf2f(hvv[r8].y)+sl.y,
                               bf2f(hvv[r8].z)+sl.z, bf2f(hvv[r8].w)+sl.w);
      int j = r0v[r8];
      const int r1 = r1v[r8];
      while(j < r1){
        int cnt = r1 - j; if(cnt > 4) cnt = 4;
        unsigned pv0 = 0, pv1 = 0, pv2 = 0, pv3 = 0;
        pv0 = pl[j];
        if(cnt > 1) pv1 = pl[j+1];
        if(cnt > 2) pv2 = pl[j+2];
        if(cnt > 3) pv3 = pl[j+3];
        short4 h0 = {}, h1 = {}, h2 = {}, h3 = {};
        h0 = *(const short4*)(hin + (size_t)(pv0 & 0x3FFFF)*HS + d4);
        if(cnt > 1) h1 = *(const short4*)(hin + (size_t)(pv1 & 0x3FFFF)*HS + d4);
        if(cnt > 2) h2 = *(const short4*)(hin + (size_t)(pv2 & 0x3FFFF)*HS + d4);
        if(cnt > 3) h3 = *(const short4*)(hin + (size_t)(pv3 & 0x3FFFF)*HS + d4);
        {
          const float4 ee = *(const float4*)(eet + (pv0 >> 18)*128 + d4);
          acc.x += bf2f(h0.x)+ee.x; acc.y += bf2f(h0.y)+ee.y;
          acc.z += bf2f(h0.z)+ee.z; acc.w += bf2f(h0.w)+ee.w;
        }
        if(cnt > 1){
          const float4 ee = *(const float4*)(eet + (pv1 >> 18)*128 + d4);
          acc.x += bf2f(h1.x)+ee.x; acc.y += bf2f(h1.y)+ee.y;
          acc.z += bf2f(h1.z)+ee.z; acc.w += bf2f(h1.w)+ee.w;
        }
        if(cnt > 2){
          const float4 ee = *(const float4*)(eet + (pv2 >> 18)*128 + d4);
          acc.x += bf2f(h2.x)+ee.x; acc.y += bf2f(h2.y)+ee.y;
          acc.z += bf2f(h2.z)+ee.z; acc.w += bf2f(h2.w)+ee.w;
        }
        if(cnt > 3){
          const float4 ee = *(const float4*)(eet + (pv3 >> 18)*128 + d4);
          acc.x += bf2f(h3.x)+ee.x; acc.y += bf2f(h3.y)+ee.y;
          acc.z += bf2f(h3.z)+ee.z; acc.w += bf2f(h3.w)+ee.w;
        }
        j += 4;
      }
      short4 o; o.x=f2bf(acc.x); o.y=f2bf(acc.y); o.z=f2bf(acc.z); o.w=f2bf(acc.w);
      *(short4*)(agg_s + (r8*8 + rl)*136 + d4) = o;
    }
  }
  __syncthreads();

  const int lane = threadIdx.x & 63, wave = threadIdx.x >> 6;
  const int l16 = lane & 15, lq = lane >> 4;

  f32x4 acc2[4][2] = {};
#pragma unroll 1
  for(int half = 0; half < 2; half++){
    if(half) __syncthreads();   // protect hid_s from previous-half readers

    // ---- phase 1: hidden half = relu(agg @ W1[:, half*128 + ...] + b1) ----
    f32x4 acc1[4][2] = {};
#pragma unroll
    for(int ks = 0; ks < 4; ks++){
      const int k0 = ks*32 + lq*8;
      bf16x8 a[4];
#pragma unroll
      for(int rt = 0; rt < 4; rt++)
        a[rt] = *(const bf16x8*)(agg_s + (rt*16 + l16)*136 + k0);
#pragma unroll
      for(int ct = 0; ct < 2; ct++){
        const int ch = half*128 + wave*32 + ct*16 + l16;   // global hidden col
        bf16x8 b = *(const bf16x8*)(w1t + ch*136 + k0);
#pragma unroll
        for(int rt = 0; rt < 4; rt++)
          acc1[rt][ct] = __builtin_amdgcn_mfma_f32_16x16x32_bf16(a[rt], b, acc1[rt][ct], 0, 0, 0);
      }
    }
#pragma unroll
    for(int ct = 0; ct < 2; ct++){
      const int ch = half*128 + wave*32 + ct*16 + l16;
      const int cl = wave*32 + ct*16 + l16;                // local col in hid_s
      const float bs = ldf(b1, boff1 + ch, f);
#pragma unroll
      for(int rt = 0; rt < 4; rt++){
#pragma unroll
        for(int i2 = 0; i2 < 4; i2++){
          float v = fmaxf(acc1[rt][ct][i2] + bs, 0.f);
          hid_s[(rt*16 + lq*4 + i2)*136 + cl] = f2bf(v);
        }
      }
    }
    __syncthreads();

    // ---- phase 2: acc2 += hidden_half @ W2[half*128 .. , :] ----
#pragma unroll
    for(int ks = 0; ks < 4; ks++){
      const int kl = ks*32 + lq*8;            // local k in hid_s
      const int kg = half*128 + kl;           // global k for w2t
      bf16x8 a[4];
#pragma unroll
      for(int rt = 0; rt < 4; rt++)
        a[rt] = *(const bf16x8*)(hid_s + (rt*16 + l16)*136 + kl);
#pragma unroll
      for(int ct = 0; ct < 2; ct++){
        const int col = wave*32 + ct*16 + l16;
        bf16x8 b = *(const bf16x8*)(w2t + col*264 + kg);
#pragma unroll
        for(int rt = 0; rt < 4; rt++)
          acc2[rt][ct] = __builtin_amdgcn_mfma_f32_16x16x32_bf16(a[rt], b, acc2[rt][ct], 0, 0, 0);
      }
    }
  }

  // ---- epilogue ----
#pragma unroll
  for(int ct = 0; ct < 2; ct++){
    const int col = wave*32 + ct*16 + l16;
    const float bs = ldf(b2, boff2 + col, f);
#pragma unroll
    for(int rt = 0; rt < 4; rt++){
#pragma unroll
      for(int i2 = 0; i2 < 4; i2++){
        int row = rowbase + rt*16 + lq*4 + i2;
        if(row < M){
          float v = fmaxf(acc2[rt][ct][i2] + bs, 0.f);
          hout[(size_t)row*128 + col] = f2bf(v);
        }
      }
    }
  }
}

// x_struct -> catb[:,128:256] (bf16) + BN1 stats for cols 128..255; ind sorted
DEV int lower_bound_i(const int* a, int len, int v){
  int lo = 0, hi = len;
  while(lo < hi){ int mid = (lo+hi) >> 1; if(a[mid] < v) lo = mid+1; else hi = mid; }
  return lo;
}
__global__ __launch_bounds__(256) void xstruct_k(const short* __restrict__ h,
                          const int* __restrict__ ind, short* __restrict__ catb,
                          float* __restrict__ stats, int M, int N){
  const int nl = threadIdx.x >> 5, d4 = (threadIdx.x & 31) << 2;
  float4 s = make_float4(0,0,0,0), q = make_float4(0,0,0,0);
  for(int n = blockIdx.x*8 + nl; n < N; n += gridDim.x*8){
    int l0 = lower_bound_i(ind, M, n);
    int l1 = lower_bound_i(ind, M, n+1);
    float4 acc = make_float4(0.f, 0.f, 0.f, 0.f);
    for(int m = l0; m < l1; m++){
      short4 hv = *(const short4*)(h + (size_t)m*128 + d4);
      acc.x += bf2f(hv.x); acc.y += bf2f(hv.y);
      acc.z += bf2f(hv.z); acc.w += bf2f(hv.w);
    }
    short4 o; o.x=f2bf(acc.x); o.y=f2bf(acc.y); o.z=f2bf(acc.z); o.w=f2bf(acc.w);
    *(short4*)(catb + (size_t)n*256 + 128 + d4) = o;
    float4 fo = make_float4(bf2f(o.x), bf2f(o.y), bf2f(o.z), bf2f(o.w));
    s.x += fo.x; s.y += fo.y; s.z += fo.z; s.w += fo.w;
    q.x += fo.x*fo.x; q.y += fo.y*fo.y; q.z += fo.z*fo.z; q.w += fo.w*fo.w;
  }
  __shared__ float sm[256][8];
  sm[threadIdx.x][0]=s.x; sm[threadIdx.x][1]=s.y; sm[threadIdx.x][2]=s.z; sm[threadIdx.x][3]=s.w;
  sm[threadIdx.x][4]=q.x; sm[threadIdx.x][5]=q.y; sm[threadIdx.x][6]=q.z; sm[threadIdx.x][7]=q.w;
  __syncthreads();
  if(threadIdx.x < 32){
    int c4 = threadIdx.x << 2;
    float acc[8];
#pragma unroll
    for(int j = 0; j < 8; j++) acc[j] = sm[threadIdx.x][j];
    for(int g = 1; g < 8; g++)
#pragma unroll
      for(int j = 0; j < 8; j++) acc[j] += sm[g*32 + threadIdx.x][j];
#pragma unroll
    for(int t = 0; t < 4; t++) atomicAdd(&stats[128 + c4+t], acc[t]);
#pragma unroll
    for(int t = 0; t < 4; t++) atomicAdd(&stats[384 + c4+t], acc[4+t]);
  }
}

__global__ void bnfin_k(const float* __restrict__ stats, const void* __restrict__ gamma,
                        const void* __restrict__ beta, const int* __restrict__ flagp,
                        float* __restrict__ scl, float* __restrict__ sft,
                        int cols, float invN){
  int c = threadIdx.x; if(c >= cols) return;
  int f = *flagp;
  float mean = stats[c]*invN;
  float var  = stats[cols+c]*invN - mean*mean;
  float s = ldf(gamma, c, f) * rsqrtf(var + 1e-5f);
  scl[c] = s; sft[c] = ldf(beta, c, f) - mean*s;
}

// out = BN2(out2) stored per output dtype flag
__global__ void bn2apply_k(const float* __restrict__ out2, const float* __restrict__ scl,
                           const float* __restrict__ sft, const int* __restrict__ flagp,
                           void* __restrict__ outv, int N){
  int i = blockIdx.x*blockDim.x + threadIdx.x;
  if(i >= N*32) return;
  int f = *flagp;
  int n = i >> 5, d4 = (i & 31) << 2;
  size_t idx = (size_t)n*128 + d4;
  float4 v = *(const float4*)(out2 + idx);
  float4 o = make_float4(v.x*scl[d4+0] + sft[d4+0], v.y*scl[d4+1] + sft[d4+1],
                         v.z*scl[d4+2] + sft[d4+2], v.w*scl[d4+3] + sft[d4+3]);
  if(f){
    *(float4*)((float*)outv + idx) = o;
  } else {
    short4 s; s.x=f2bf(o.x); s.y=f2bf(o.y); s.z=f2bf(o.z); s.w=f2bf(o.w);
    *(short4*)((short*)outv + idx) = s;
  }
}

// ---------------- MFMA GEMM (projection) + optional fused BN2 stats ----------------
template<int KK, int NN, int AMODE, bool RELU, bool OFLOAT, bool STATS>
__global__ __launch_bounds__(256) void gemm_k(const void* __restrict__ Av,
        const short* __restrict__ BT, const void* __restrict__ bias, long boff,
        const int* __restrict__ flagp,
        const float* __restrict__ scl, const float* __restrict__ sft,
        void* __restrict__ Ov, float* __restrict__ stats2, int Mrows){
  constexpr int CT  = NN/64;
  constexpr int KS  = KK/32;
  constexpr int LDB = KK + 8;
  __shared__ alignas(16) short bt[NN*LDB];
  {
    const float4* s = (const float4*)BT;
    float4* d = (float4*)bt;
    constexpr int total = NN*LDB*2/16;
    for(int i = threadIdx.x; i < total; i += 256) d[i] = s[i];
  }
  const int f = *flagp;
  __syncthreads();

  const int lane = threadIdx.x & 63, wave = threadIdx.x >> 6;
  const int l16 = lane & 15, lq = lane >> 4;
  const int rowbase = blockIdx.x * 64;
  const int colbase = wave * (NN/4);

  f32x4 acc[4][CT] = {};
  for(int ks = 0; ks < KS; ks++){
    const int k0 = ks*32 + lq*8;
    bf16x8 a[4];
#pragma unroll
    for(int rt = 0; rt < 4; rt++){
      int row = rowbase + rt*16 + l16;
      if(row >= Mrows) row = Mrows - 1;
      bf16x8 av = *(const bf16x8*)((const short*)Av + (size_t)row*KK + k0);
      if constexpr (AMODE == 2){
        bf16x8 aw;
#pragma unroll
        for(int j = 0; j < 8; j++) aw[j] = f2bf(bf2f(av[j])*scl[k0+j] + sft[k0+j]);
        a[rt] = aw;
      } else {
        a[rt] = av;
      }
    }
#pragma unroll
    for(int ct = 0; ct < CT; ct++){
      bf16x8 b = *(const bf16x8*)(bt + (colbase + ct*16 + l16)*LDB + k0);
#pragma unroll
      for(int rt = 0; rt < 4; rt++)
        acc[rt][ct] = __builtin_amdgcn_mfma_f32_16x16x32_bf16(a[rt], b, acc[rt][ct], 0, 0, 0);
    }
  }
#pragma unroll
  for(int ct = 0; ct < CT; ct++){
    const int col = colbase + ct*16 + l16;
    const float bs = ldf(bias, boff + col, f);
    float cs = 0.f, cq = 0.f;
#pragma unroll
    for(int rt = 0; rt < 4; rt++){
#pragma unroll
      for(int i2 = 0; i2 < 4; i2++){
        int row = rowbase + rt*16 + lq*4 + i2;
        if(row < Mrows){
          float v = acc[rt][ct][i2] + bs;
          if constexpr (RELU) v = fmaxf(v, 0.f);
          if constexpr (OFLOAT) ((float*)Ov)[(size_t)row*NN + col] = v;
          else ((short*)Ov)[(size_t)row*NN + col] = f2bf(v);
          if constexpr (STATS){ cs += v; cq += v*v; }
        }
      }
    }
    if constexpr (STATS){
      cs += __shfl_xor(cs, 16); cq += __shfl_xor(cq, 16);
      cs += __shfl_xor(cs, 32); cq += __shfl_xor(cq, 32);
      if(lq == 0){
        atomicAdd(&stats2[col], cs);
        atomicAdd(&stats2[NN + col], cq);
      }
    }
  }
}

extern "C" void kernel_launch(void* const* d_in, const int* in_sizes, int n_in,
                              void* d_out, int out_size, void* d_ws, size_t ws_size,
                              hipStream_t stream){
  const int*  x    = (const int*)d_in[0];
  const int*  sgn  = (const int*)d_in[3];
  const int*  sge  = (const int*)d_in[4];
  const int*  sga  = (const int*)d_in[5];
  const int*  sgi  = (const int*)d_in[6];
  const void* xe1  = d_in[7];
  const void* xe2  = d_in[8];
  const void* ee1  = d_in[9];   // [2][6][128]
  const void* ee2  = d_in[10];  // [2][3][128]
  const void* W1   = d_in[11];  // [2][128][256]
  const void* b1   = d_in[12];  // [2][256]
  const void* W2   = d_in[13];  // [2][256][128]
  const void* b2   = d_in[14];  // [2][128]
  const void* g1   = d_in[15];
  const void* be1  = d_in[16];
  const void* Wp   = d_in[17];  // [256][128]
  const void* bp   = d_in[18];
  const void* g2   = d_in[19];
  const void* be2  = d_in[20];

  const int N = in_sizes[0] / 2;     // 20000
  const int M = in_sizes[3];         // 200000
  const int E = in_sizes[4] / 2;     // 400000
  const int* esrc = sge;
  const int* edst = sge + E;

  size_t off = 0;
  auto alloc = [&](size_t bytes)->void*{
    void* p = (char*)d_ws + off;
    off += (bytes + 255) & ~(size_t)255;
    return p;
  };
  int*      flag   = (int*)alloc(4);
  short*    catb   = (short*)alloc((size_t)N*256*2);   // bf16 [N][256]: [orig | x_struct]
  short*    ha     = (short*)alloc((size_t)M*128*2);   // h ping
  short*    hb     = (short*)alloc((size_t)M*128*2);   // h pong (also out2 alias)
  short*    w1t    = (short*)alloc((size_t)2*256*136*2);
  short*    w2t    = (short*)alloc((size_t)2*128*264*2);
  short*    wpt    = (short*)alloc((size_t)128*264*2);
  float*    stats  = (float*)alloc((size_t)(512+256)*4);
  float*    scl1   = (float*)alloc(256*4);
  float*    sft1   = (float*)alloc(256*4);
  float*    scl2   = (float*)alloc(128*4);
  float*    sft2   = (float*)alloc(128*4);
  int*      rowptr = (int*)alloc((size_t)(M+1)*4);
  int*      degcur = (int*)alloc((size_t)M*4);         // deg, then cursor (rewritten by scanC)
  unsigned* pl0    = (unsigned*)alloc((size_t)E*4);    // catb-space payload
  unsigned* pl1    = (unsigned*)alloc((size_t)E*4);    // h-space payload
  int*      bsum   = (int*)alloc(256*4);
  float*    eet    = (float*)alloc((size_t)2*10*128*4);
  float*    out2   = (float*)hb;    // hb dead after layer1 (hb -> ha)

  if(off > ws_size) return;

  const int NB = 240;
  const int chunk = (M + NB - 1) / NB;
  const int ept = (chunk + 255) / 256;

  (void)hipMemsetAsync(stats, 0, (512+256)*4, stream);
  (void)hipMemsetAsync(degcur, 0, (size_t)M*4, stream);

  probe_k<<<1, 256, 0, stream>>>(xe1, 120*128, flag);

  // CSR build (edges static across layers): hist -> scanA -> scanC -> fill
  hist_k<<<(E+255)/256, 256, 0, stream>>>(edst, degcur, E);
  scanA_k<<<NB, 256, 0, stream>>>(degcur, bsum, M, chunk, ept);
  scanC_k<<<NB, 256, 0, stream>>>(degcur, bsum, rowptr, degcur, M, chunk, ept, E);
  fill_k<<<(E+255)/256, 256, 0, stream>>>(esrc, edst, sga, sgn, degcur, pl0, pl1, E);

  // one-shot prep: eet tables + weight transposes
  prep_k<<<(166400+255)/256, 256, 0, stream>>>(ee1, ee2, W1, W2, Wp, flag,
      eet, w1t, w2t, wpt);

  // embed (+ BN1 stats cols 0..127)
  embed_k<<<256, 256, 0, stream>>>(x, xe1, xe2, flag, catb, stats, N);

  // fused GIN layers: catb --(gather folded)--> hb -> ha
  layer_k<256><<<(M+63)/64, 256, 0, stream>>>(catb, sgn, rowptr, pl0, eet,
      w1t, w2t, b1, 0, b2, 0, flag, hb, M);
  layer_k<128><<<(M+63)/64, 256, 0, stream>>>(hb, nullptr, rowptr, pl1, eet + 1280,
      w1t + (size_t)256*136, w2t + (size_t)128*264, b1, 256, b2, 128, flag, ha, M);

  // x_struct (+ BN1 stats cols 128..255)
  xstruct_k<<<256, 256, 0, stream>>>(ha, sgi, catb, stats, M, N);

  bnfin_k<<<1, 256, 0, stream>>>(stats, g1, be1, flag, scl1, sft1, 256, 1.0f/N);

  // projection GEMM with folded BN1 on A and fused BN2 stats on output
  gemm_k<256,128,2,false,true,true><<<(N+63)/64, 256, 0, stream>>>(
      catb, wpt, bp, 0, flag, scl1, sft1, out2, stats + 512, N);

  bnfin_k<<<1, 128, 0, stream>>>(stats + 512, g2, be2, flag, scl2, sft2, 128, 1.0f/N);

  bn2apply_k<<<(N*32+255)/256, 256, 0, stream>>>(out2, scl2, sft2, flag, d_out, N);
}

// Round 13
// 359.097 us; speedup vs baseline: 1.3554x; 1.3350x over previous
//
#include <hip/hip_runtime.h>
#include <hip/hip_bf16.h>

#define DEV __device__ __forceinline__

typedef __attribute__((ext_vector_type(8))) short bf16x8;
typedef __attribute__((ext_vector_type(4))) float f32x4;

DEV float bf2f(short s){ unsigned u = ((unsigned)(unsigned short)s) << 16; return __builtin_bit_cast(float, u); }
DEV short f2bf(float f){ __hip_bfloat16 h = __float2bfloat16(f); return __builtin_bit_cast(short, h); }

// flag-dispatched loads from external float inputs (f=1: fp32, f=0: bf16)
DEV float ldf(const void* p, long i, int f){
  return f ? ((const float*)p)[i] : bf2f(((const short*)p)[i]);
}
DEV float4 ldf4(const void* p, long i, int f){   // i must be a multiple of 4
  if(f) return *(const float4*)((const float*)p + i);
  short4 v = *(const short4*)((const short*)p + i);
  return make_float4(bf2f(v.x), bf2f(v.y), bf2f(v.z), bf2f(v.w));
}

// Detect external float dtype: fp32 reinterpreted as bf16 shorts gives huge
// max over x_emb1's even shorts; genuine bf16 gives ~0.1.
__global__ void probe_k(const void* __restrict__ xe1, int nelem, int* __restrict__ flag){
  const short* p = (const short*)xe1;
  float m = 0.f;
  for(int i = threadIdx.x*2; i < nelem; i += 512){
    float v = fabsf(bf2f(p[i]));
    if(v > m) m = v;
  }
  for(int o = 32; o > 0; o >>= 1) m = fmaxf(m, __shfl_xor(m, o));
  __shared__ float sm[4];
  if((threadIdx.x & 63) == 0) sm[threadIdx.x >> 6] = m;
  __syncthreads();
  if(threadIdx.x == 0){
    float mm = fmaxf(fmaxf(sm[0], sm[1]), fmaxf(sm[2], sm[3]));
    flag[0] = (mm > 1000.f) ? 1 : 0;
  }
}

// ---- one-shot prep: eet tables (both layers) + w1t/w2t/wpt transposes ----
__global__ void prep_k(const void* __restrict__ ee1, const void* __restrict__ ee2,
                       const void* __restrict__ W1, const void* __restrict__ W2,
                       const void* __restrict__ Wp, const int* __restrict__ flagp,
                       float* __restrict__ eet, short* __restrict__ w1t,
                       short* __restrict__ w2t, short* __restrict__ wpt){
  const int f = *flagp;
  int i = blockIdx.x*blockDim.x + threadIdx.x;
  if(i < 2560){                                  // eet: [2][10][128]
    int l = i / 1280, j = i % 1280, r = j >> 7, d = j & 127;
    int o1 = l*768, o2 = l*384;
    float v;
    if(r == 9) v = ldf(ee1, o1 + 4*128 + d, f) + ldf(ee2, o2 + d, f);
    else       v = ldf(ee1, o1 + (r/3)*128 + d, f) + ldf(ee2, o2 + (r%3)*128 + d, f);
    eet[l*1280 + r*128 + d] = v;
  } else if(i < 2560 + 65536){                   // w1t: [2] 128x256 -> [256][136]
    int j = i - 2560; int l = j >> 15; j &= 32767;
    int k = j >> 8, n = j & 255;
    w1t[(size_t)l*256*136 + n*136 + k] = f2bf(ldf(W1, (long)l*32768 + j, f));
  } else if(i < 2560 + 131072){                  // w2t: [2] 256x128 -> [128][264]
    int j = i - 2560 - 65536; int l = j >> 15; j &= 32767;
    int k = j >> 7, n = j & 127;
    w2t[(size_t)l*128*264 + n*264 + k] = f2bf(ldf(W2, (long)l*32768 + j, f));
  } else if(i < 2560 + 131072 + 32768){          // wpt: 256x128 -> [128][264]
    int j = i - 2560 - 131072;
    int k = j >> 7, n = j & 127;
    wpt[n*264 + k] = f2bf(ldf(Wp, (long)j, f));
  }
}

// origin_h -> catb[:, 0:128] (bf16)
__global__ void embed_k(const int* __restrict__ x, const void* __restrict__ e1,
                        const void* __restrict__ e2, const int* __restrict__ flagp,
                        short* __restrict__ catb, int N){
  int i = blockIdx.x*blockDim.x + threadIdx.x;
  if(i >= N*32) return;
  int f = *flagp;
  int n = i >> 5, d4 = (i & 31) << 2;
  int a = x[2*n], b = x[2*n+1];
  float4 v1 = ldf4(e1, a*128 + d4, f);
  float4 v2 = ldf4(e2, b*128 + d4, f);
  short4 o; o.x=f2bf(v1.x+v2.x); o.y=f2bf(v1.y+v2.y);
  o.z=f2bf(v1.z+v2.z); o.w=f2bf(v1.w+v2.w);
  *(short4*)(catb + (size_t)n*256 + d4) = o;
}

// ---------- CSR build (once; dst static across layers) ----------
__global__ void hist_k(const int* __restrict__ dst, int* __restrict__ deg, int E){
  int e = blockIdx.x*blockDim.x + threadIdx.x;
  if(e < E) atomicAdd(&deg[dst[e]], 1);
}
__global__ void scanA_k(const int* __restrict__ deg, int* __restrict__ bsum,
                        int M, int chunk, int ept){
  __shared__ int sm[256];
  int lo = blockIdx.x*chunk;
  int a = lo + threadIdx.x*ept, b = min(min(M, lo+chunk), a+ept);
  int s = 0;
  for(int i = a; i < b; i++) s += deg[i];
  sm[threadIdx.x] = s; __syncthreads();
  for(int o = 128; o > 0; o >>= 1){
    if(threadIdx.x < o) sm[threadIdx.x] += sm[threadIdx.x+o];
    __syncthreads();
  }
  if(threadIdx.x == 0) bsum[blockIdx.x] = sm[0];
}
// scanC: per-block prefix from bsum (inline) + rowptr + cursor
__global__ void scanC_k(const int* __restrict__ deg, const int* __restrict__ bsum,
                        int* __restrict__ rowptr, int* __restrict__ cursor,
                        int M, int chunk, int ept, int E){
  __shared__ int sm[256];
  const int t = threadIdx.x;
  sm[t] = (t < blockIdx.x) ? bsum[t] : 0;
  __syncthreads();
  for(int o = 128; o > 0; o >>= 1){
    if(t < o) sm[t] += sm[t+o];
    __syncthreads();
  }
  const int bpre = sm[0];
  __syncthreads();
  int lo = blockIdx.x*chunk;
  int a = lo + t*ept, b = min(min(M, lo+chunk), a+ept);
  int s = 0;
  for(int i = a; i < b; i++) s += deg[i];
  int v = s;
  sm[t] = v; __syncthreads();
  for(int o = 1; o < 256; o <<= 1){
    int u = (t >= o) ? sm[t-o] : 0; __syncthreads();
    sm[t] += u; __syncthreads();
  }
  int base = bpre + sm[t] - v;
  for(int i = a; i < b; i++){
    int d = deg[i];                 // read BEFORE cursor write (may alias deg)
    rowptr[i] = base; cursor[i] = base; base += d;
  }
  if(blockIdx.x == 0 && t == 0) rowptr[M] = E;
}
// payloads: pl1[pos] = src | (attr_idx<<18)        (h-space, layer 1)
//           pl0[pos] = sgn[src] | (attr_idx<<18)   (catb-space, layer 0)
__global__ void fill_k(const int* __restrict__ src, const int* __restrict__ dst,
                       const int* __restrict__ attr, const int* __restrict__ sgn,
                       int* __restrict__ cursor,
                       unsigned* __restrict__ pl0, unsigned* __restrict__ pl1, int E){
  int e = blockIdx.x*blockDim.x + threadIdx.x;
  if(e >= E) return;
  int t = dst[e];
  int pos = atomicAdd(&cursor[t], 1);
  unsigned idx = (unsigned)(attr[2*e]*3 + attr[2*e+1]);
  int s = src[e];
  pl1[pos] = (unsigned)s | (idx << 18);
  pl0[pos] = (unsigned)sgn[s] | (idx << 18);
}

// ---------------- fused GIN layer: 64 rows, 512 threads (8 waves), 34.8KB ----------------
// HS = row stride of hin (256 for catb, 128 for h). selfidx: optional m->row map.
// 8 waves/block: more resident waves per CU if block-count (not LDS) limits residency.
template<int HS>
__global__ __launch_bounds__(512, 6) void layer_k(
    const short* __restrict__ hin, const int* __restrict__ selfidx,
    const int* __restrict__ rowptr, const unsigned* __restrict__ pl,
    const float* __restrict__ eet,
    const short* __restrict__ w1t, const short* __restrict__ w2t,
    const void* __restrict__ b1, long boff1,
    const void* __restrict__ b2, long boff2,
    const int* __restrict__ flagp, short* __restrict__ hout, int M){
  __shared__ alignas(16) short agg_s[64*136];   // 272B stride: 2-way banks (free)
  __shared__ alignas(16) short hid_s[64*136];   // one 128-col half of hidden
  const int f = *flagp;
  const int rowbase = blockIdx.x*64;

  // ---- phase 0: gather-aggregate; 16 groups x 4 rows, independent chains ----
  {
    const int rl = threadIdx.x >> 5;          // 0..15 (row group)
    const int d4 = (threadIdx.x & 31) << 2;
    const float4 sl = *(const float4*)(eet + 9*128 + d4);
    int r0v[4], r1v[4];
    short4 hvv[4];
#pragma unroll
    for(int r8 = 0; r8 < 4; r8++){
      int m = rowbase + r8*16 + rl; if(m >= M) m = M-1;
      int self = selfidx ? selfidx[m] : m;
      hvv[r8] = *(const short4*)(hin + (size_t)self*HS + d4);
      r0v[r8] = rowptr[m];
      r1v[r8] = rowptr[m+1];
    }
#pragma unroll
    for(int r8 = 0; r8 < 4; r8++){
      float4 acc = make_float4(bf2f(hvv[r8].x)+sl.x, bf2f(hvv[r8].y)+sl.y,
                               bf2f(hvv[r8].z)+sl.z, bf2f(hvv[r8].w)+sl.w);
      int j = r0v[r8];
      const int r1 = r1v[r8];
      while(j < r1){
        int cnt = r1 - j; if(cnt > 4) cnt = 4;
        unsigned pv0 = 0, pv1 = 0, pv2 = 0, pv3 = 0;
        pv0 = pl[j];
        if(cnt > 1) pv1 = pl[j+1];
        if(cnt > 2) pv2 = pl[j+2];
        if(cnt > 3) pv3 = pl[j+3];
        short4 h0 = {}, h1 = {}, h2 = {}, h3 = {};
        h0 = *(const short4*)(hin + (size_t)(pv0 & 0x3FFFF)*HS + d4);
        if(cnt > 1) h1 = *(const short4*)(hin + (size_t)(pv1 & 0x3FFFF)*HS + d4);
        if(cnt > 2) h2 = *(const short4*)(hin + (size_t)(pv2 & 0x3FFFF)*HS + d4);
        if(cnt > 3) h3 = *(const short4*)(hin + (size_t)(pv3 & 0x3FFFF)*HS + d4);
        {
          const float4 ee = *(const float4*)(eet + (pv0 >> 18)*128 + d4);
          acc.x += bf2f(h0.x)+ee.x; acc.y += bf2f(h0.y)+ee.y;
          acc.z += bf2f(h0.z)+ee.z; acc.w += bf2f(h0.w)+ee.w;
        }
        if(cnt > 1){
          const float4 ee = *(const float4*)(eet + (pv1 >> 18)*128 + d4);
          acc.x += bf2f(h1.x)+ee.x; acc.y += bf2f(h1.y)+ee.y;
          acc.z += bf2f(h1.z)+ee.z; acc.w += bf2f(h1.w)+ee.w;
        }
        if(cnt > 2){
          const float4 ee = *(const float4*)(eet + (pv2 >> 18)*128 + d4);
          acc.x += bf2f(h2.x)+ee.x; acc.y += bf2f(h2.y)+ee.y;
          acc.z += bf2f(h2.z)+ee.z; acc.w += bf2f(h2.w)+ee.w;
        }
        if(cnt > 3){
          const float4 ee = *(const float4*)(eet + (pv3 >> 18)*128 + d4);
          acc.x += bf2f(h3.x)+ee.x; acc.y += bf2f(h3.y)+ee.y;
          acc.z += bf2f(h3.z)+ee.z; acc.w += bf2f(h3.w)+ee.w;
        }
        j += 4;
      }
      short4 o; o.x=f2bf(acc.x); o.y=f2bf(acc.y); o.z=f2bf(acc.z); o.w=f2bf(acc.w);
      *(short4*)(agg_s + (r8*16 + rl)*136 + d4) = o;
    }
  }
  __syncthreads();

  const int lane = threadIdx.x & 63, wave = threadIdx.x >> 6;   // wave 0..7
  const int l16 = lane & 15, lq = lane >> 4;

  f32x4 acc2[4] = {};
#pragma unroll 1
  for(int half = 0; half < 2; half++){
    if(half) __syncthreads();   // protect hid_s from previous-half readers

    // ---- phase 1: hidden col-tile = relu(agg @ W1[:, half*128 + wave*16 ..] + b1) ----
    f32x4 acc1[4] = {};
#pragma unroll
    for(int ks = 0; ks < 4; ks++){
      const int k0 = ks*32 + lq*8;
      bf16x8 a[4];
#pragma unroll
      for(int rt = 0; rt < 4; rt++)
        a[rt] = *(const bf16x8*)(agg_s + (rt*16 + l16)*136 + k0);
      const int ch = half*128 + wave*16 + l16;             // global hidden col
      bf16x8 b = *(const bf16x8*)(w1t + ch*136 + k0);
#pragma unroll
      for(int rt = 0; rt < 4; rt++)
        acc1[rt] = __builtin_amdgcn_mfma_f32_16x16x32_bf16(a[rt], b, acc1[rt], 0, 0, 0);
    }
    {
      const int ch = half*128 + wave*16 + l16;
      const int cl = wave*16 + l16;                        // local col in hid_s
      const float bs = ldf(b1, boff1 + ch, f);
#pragma unroll
      for(int rt = 0; rt < 4; rt++){
#pragma unroll
        for(int i2 = 0; i2 < 4; i2++){
          float v = fmaxf(acc1[rt][i2] + bs, 0.f);
          hid_s[(rt*16 + lq*4 + i2)*136 + cl] = f2bf(v);
        }
      }
    }
    __syncthreads();

    // ---- phase 2: acc2 += hidden_half @ W2[half*128.., wave*16..] ----
#pragma unroll
    for(int ks = 0; ks < 4; ks++){
      const int kl = ks*32 + lq*8;            // local k in hid_s
      const int kg = half*128 + kl;           // global k for w2t
      bf16x8 a[4];
#pragma unroll
      for(int rt = 0; rt < 4; rt++)
        a[rt] = *(const bf16x8*)(hid_s + (rt*16 + l16)*136 + kl);
      const int col = wave*16 + l16;
      bf16x8 b = *(const bf16x8*)(w2t + col*264 + kg);
#pragma unroll
      for(int rt = 0; rt < 4; rt++)
        acc2[rt] = __builtin_amdgcn_mfma_f32_16x16x32_bf16(a[rt], b, acc2[rt], 0, 0, 0);
    }
  }

  // ---- epilogue ----
  {
    const int col = wave*16 + l16;
    const float bs = ldf(b2, boff2 + col, f);
#pragma unroll
    for(int rt = 0; rt < 4; rt++){
#pragma unroll
      for(int i2 = 0; i2 < 4; i2++){
        int row = rowbase + rt*16 + lq*4 + i2;
        if(row < M){
          float v = fmaxf(acc2[rt][i2] + bs, 0.f);
          hout[(size_t)row*128 + col] = f2bf(v);
        }
      }
    }
  }
}

// x_struct: catb[n][128+d] = sum over m with ind[m]==n of h[m][d]; ind sorted
DEV int lower_bound_i(const int* a, int len, int v){
  int lo = 0, hi = len;
  while(lo < hi){ int mid = (lo+hi) >> 1; if(a[mid] < v) lo = mid+1; else hi = mid; }
  return lo;
}
__global__ void xstruct_k(const short* __restrict__ h, const int* __restrict__ ind,
                          short* __restrict__ catb, int M, int N){
  int n = blockIdx.x*8 + (threadIdx.x >> 5);
  if(n >= N) return;
  int d4 = (threadIdx.x & 31) << 2;
  int l0 = lower_bound_i(ind, M, n);
  int l1 = lower_bound_i(ind, M, n+1);
  float4 acc = make_float4(0.f, 0.f, 0.f, 0.f);
  for(int m = l0; m < l1; m++){
    short4 hv = *(const short4*)(h + (size_t)m*128 + d4);
    acc.x += bf2f(hv.x); acc.y += bf2f(hv.y);
    acc.z += bf2f(hv.z); acc.w += bf2f(hv.w);
  }
  short4 o; o.x=f2bf(acc.x); o.y=f2bf(acc.y); o.z=f2bf(acc.z); o.w=f2bf(acc.w);
  *(short4*)(catb + (size_t)n*256 + 128 + d4) = o;
}

// ---- BN stats, stage 1: 256 blocks, vectorized, LDS-reduced, atomic finish ----
template<int COLS, bool BF>
__global__ __launch_bounds__(256) void bnstats1_k(const void* __restrict__ buf,
                          float* __restrict__ stats, int rows){
  constexpr int CG = COLS/4;        // col-groups of 4
  constexpr int RP = 256/CG;        // row-slices per block
  const int cg = threadIdx.x % CG, rs = threadIdx.x / CG;
  const int c4 = cg*4;
  float4 s = make_float4(0,0,0,0), q = make_float4(0,0,0,0);
  for(int r = blockIdx.x*RP + rs; r < rows; r += gridDim.x*RP){
    float4 v;
    if(BF){
      short4 sv = *(const short4*)((const short*)buf + (size_t)r*COLS + c4);
      v = make_float4(bf2f(sv.x), bf2f(sv.y), bf2f(sv.z), bf2f(sv.w));
    } else {
      v = *(const float4*)((const float*)buf + (size_t)r*COLS + c4);
    }
    s.x += v.x; s.y += v.y; s.z += v.z; s.w += v.w;
    q.x += v.x*v.x; q.y += v.y*v.y; q.z += v.z*v.z; q.w += v.w*v.w;
  }
  __shared__ float sm[256][8];
  sm[threadIdx.x][0]=s.x; sm[threadIdx.x][1]=s.y; sm[threadIdx.x][2]=s.z; sm[threadIdx.x][3]=s.w;
  sm[threadIdx.x][4]=q.x; sm[threadIdx.x][5]=q.y; sm[threadIdx.x][6]=q.z; sm[threadIdx.x][7]=q.w;
  __syncthreads();
  if(rs == 0){
    float acc[8];
#pragma unroll
    for(int j = 0; j < 8; j++) acc[j] = sm[cg][j];
    for(int j = 1; j < RP; j++)
#pragma unroll
      for(int t = 0; t < 8; t++) acc[t] += sm[j*CG + cg][t];
#pragma unroll
    for(int t = 0; t < 4; t++) atomicAdd(&stats[c4+t], acc[t]);
#pragma unroll
    for(int t = 0; t < 4; t++) atomicAdd(&stats[COLS + c4+t], acc[4+t]);
  }
}

__global__ void bnfin_k(const float* __restrict__ stats, const void* __restrict__ gamma,
                        const void* __restrict__ beta, const int* __restrict__ flagp,
                        float* __restrict__ scl, float* __restrict__ sft,
                        int cols, float invN){
  int c = threadIdx.x; if(c >= cols) return;
  int f = *flagp;
  float mean = stats[c]*invN;
  float var  = stats[cols+c]*invN - mean*mean;
  float s = ldf(gamma, c, f) * rsqrtf(var + 1e-5f);
  scl[c] = s; sft[c] = ldf(beta, c, f) - mean*s;
}

// out = BN2(out2) stored per output dtype flag
__global__ void bn2apply_k(const float* __restrict__ out2, const float* __restrict__ scl,
                           const float* __restrict__ sft, const int* __restrict__ flagp,
                           void* __restrict__ outv, int N){
  int i = blockIdx.x*blockDim.x + threadIdx.x;
  if(i >= N*32) return;
  int f = *flagp;
  int n = i >> 5, d4 = (i & 31) << 2;
  size_t idx = (size_t)n*128 + d4;
  float4 v = *(const float4*)(out2 + idx);
  float4 o = make_float4(v.x*scl[d4+0] + sft[d4+0], v.y*scl[d4+1] + sft[d4+1],
                         v.z*scl[d4+2] + sft[d4+2], v.w*scl[d4+3] + sft[d4+3]);
  if(f){
    *(float4*)((float*)outv + idx) = o;
  } else {
    short4 s; s.x=f2bf(o.x); s.y=f2bf(o.y); s.z=f2bf(o.z); s.w=f2bf(o.w);
    *(short4*)((short*)outv + idx) = s;
  }
}

// ---------------- MFMA GEMM (projection) + fused BN2 stats ----------------
template<int KK, int NN, int AMODE, bool RELU, bool OFLOAT, bool STATS>
__global__ __launch_bounds__(256) void gemm_k(const void* __restrict__ Av,
        const short* __restrict__ BT, const void* __restrict__ bias, long boff,
        const int* __restrict__ flagp,
        const float* __restrict__ scl, const float* __restrict__ sft,
        void* __restrict__ Ov, float* __restrict__ stats2, int Mrows){
  constexpr int CT  = NN/64;
  constexpr int KS  = KK/32;
  constexpr int LDB = KK + 8;
  __shared__ alignas(16) short bt[NN*LDB];
  {
    const float4* s = (const float4*)BT;
    float4* d = (float4*)bt;
    constexpr int total = NN*LDB*2/16;
    for(int i = threadIdx.x; i < total; i += 256) d[i] = s[i];
  }
  const int f = *flagp;
  __syncthreads();

  const int lane = threadIdx.x & 63, wave = threadIdx.x >> 6;
  const int l16 = lane & 15, lq = lane >> 4;
  const int rowbase = blockIdx.x * 64;
  const int colbase = wave * (NN/4);

  f32x4 acc[4][CT] = {};
  for(int ks = 0; ks < KS; ks++){
    const int k0 = ks*32 + lq*8;
    bf16x8 a[4];
#pragma unroll
    for(int rt = 0; rt < 4; rt++){
      int row = rowbase + rt*16 + l16;
      if(row >= Mrows) row = Mrows - 1;
      bf16x8 av = *(const bf16x8*)((const short*)Av + (size_t)row*KK + k0);
      if constexpr (AMODE == 2){
        bf16x8 aw;
#pragma unroll
        for(int j = 0; j < 8; j++) aw[j] = f2bf(bf2f(av[j])*scl[k0+j] + sft[k0+j]);
        a[rt] = aw;
      } else {
        a[rt] = av;
      }
    }
#pragma unroll
    for(int ct = 0; ct < CT; ct++){
      bf16x8 b = *(const bf16x8*)(bt + (colbase + ct*16 + l16)*LDB + k0);
#pragma unroll
      for(int rt = 0; rt < 4; rt++)
        acc[rt][ct] = __builtin_amdgcn_mfma_f32_16x16x32_bf16(a[rt], b, acc[rt][ct], 0, 0, 0);
    }
  }
#pragma unroll
  for(int ct = 0; ct < CT; ct++){
    const int col = colbase + ct*16 + l16;
    const float bs = ldf(bias, boff + col, f);
    float cs = 0.f, cq = 0.f;
#pragma unroll
    for(int rt = 0; rt < 4; rt++){
#pragma unroll
      for(int i2 = 0; i2 < 4; i2++){
        int row = rowbase + rt*16 + lq*4 + i2;
        if(row < Mrows){
          float v = acc[rt][ct][i2] + bs;
          if constexpr (RELU) v = fmaxf(v, 0.f);
          if constexpr (OFLOAT) ((float*)Ov)[(size_t)row*NN + col] = v;
          else ((short*)Ov)[(size_t)row*NN + col] = f2bf(v);
          if constexpr (STATS){ cs += v; cq += v*v; }
        }
      }
    }
    if constexpr (STATS){
      cs += __shfl_xor(cs, 16); cq += __shfl_xor(cq, 16);
      cs += __shfl_xor(cs, 32); cq += __shfl_xor(cq, 32);
      if(lq == 0){
        atomicAdd(&stats2[col], cs);
        atomicAdd(&stats2[NN + col], cq);
      }
    }
  }
}

extern "C" void kernel_launch(void* const* d_in, const int* in_sizes, int n_in,
                              void* d_out, int out_size, void* d_ws, size_t ws_size,
                              hipStream_t stream){
  const int*  x    = (const int*)d_in[0];
  const int*  sgn  = (const int*)d_in[3];
  const int*  sge  = (const int*)d_in[4];
  const int*  sga  = (const int*)d_in[5];
  const int*  sgi  = (const int*)d_in[6];
  const void* xe1  = d_in[7];
  const void* xe2  = d_in[8];
  const void* ee1  = d_in[9];   // [2][6][128]
  const void* ee2  = d_in[10];  // [2][3][128]
  const void* W1   = d_in[11];  // [2][128][256]
  const void* b1   = d_in[12];  // [2][256]
  const void* W2   = d_in[13];  // [2][256][128]
  const void* b2   = d_in[14];  // [2][128]
  const void* g1   = d_in[15];
  const void* be1  = d_in[16];
  const void* Wp   = d_in[17];  // [256][128]
  const void* bp   = d_in[18];
  const void* g2   = d_in[19];
  const void* be2  = d_in[20];

  const int N = in_sizes[0] / 2;     // 20000
  const int M = in_sizes[3];         // 200000
  const int E = in_sizes[4] / 2;     // 400000
  const int* esrc = sge;
  const int* edst = sge + E;

  size_t off = 0;
  auto alloc = [&](size_t bytes)->void*{
    void* p = (char*)d_ws + off;
    off += (bytes + 255) & ~(size_t)255;
    return p;
  };
  int*      flag   = (int*)alloc(4);
  short*    catb   = (short*)alloc((size_t)N*256*2);   // bf16 [N][256]: [orig | x_struct]
  short*    ha     = (short*)alloc((size_t)M*128*2);   // h ping
  short*    hb     = (short*)alloc((size_t)M*128*2);   // h pong (also out2 alias)
  short*    w1t    = (short*)alloc((size_t)2*256*136*2);
  short*    w2t    = (short*)alloc((size_t)2*128*264*2);
  short*    wpt    = (short*)alloc((size_t)128*264*2);
  float*    stats  = (float*)alloc((size_t)(512+256)*4);
  float*    scl1   = (float*)alloc(256*4);
  float*    sft1   = (float*)alloc(256*4);
  float*    scl2   = (float*)alloc(128*4);
  float*    sft2   = (float*)alloc(128*4);
  int*      rowptr = (int*)alloc((size_t)(M+1)*4);
  int*      degcur = (int*)alloc((size_t)M*4);         // deg, then cursor (rewritten by scanC)
  unsigned* pl0    = (unsigned*)alloc((size_t)E*4);    // catb-space payload
  unsigned* pl1    = (unsigned*)alloc((size_t)E*4);    // h-space payload
  int*      bsum   = (int*)alloc(256*4);
  float*    eet    = (float*)alloc((size_t)2*10*128*4);
  float*    out2   = (float*)hb;    // hb dead after layer1 (hb -> ha)

  if(off > ws_size) return;

  const int NB = 240;
  const int chunk = (M + NB - 1) / NB;
  const int ept = (chunk + 255) / 256;

  (void)hipMemsetAsync(stats, 0, (512+256)*4, stream);
  (void)hipMemsetAsync(degcur, 0, (size_t)M*4, stream);

  probe_k<<<1, 256, 0, stream>>>(xe1, 120*128, flag);

  // CSR build (edges static across layers): hist -> scanA -> scanC -> fill
  hist_k<<<(E+255)/256, 256, 0, stream>>>(edst, degcur, E);
  scanA_k<<<NB, 256, 0, stream>>>(degcur, bsum, M, chunk, ept);
  scanC_k<<<NB, 256, 0, stream>>>(degcur, bsum, rowptr, degcur, M, chunk, ept, E);
  fill_k<<<(E+255)/256, 256, 0, stream>>>(esrc, edst, sga, sgn, degcur, pl0, pl1, E);

  // one-shot prep: eet tables + weight transposes
  prep_k<<<(166400+255)/256, 256, 0, stream>>>(ee1, ee2, W1, W2, Wp, flag,
      eet, w1t, w2t, wpt);

  embed_k<<<(N*32+255)/256, 256, 0, stream>>>(x, xe1, xe2, flag, catb, N);

  // fused GIN layers (512-thread blocks): catb --(gather folded)--> hb -> ha
  layer_k<256><<<(M+63)/64, 512, 0, stream>>>(catb, sgn, rowptr, pl0, eet,
      w1t, w2t, b1, 0, b2, 0, flag, hb, M);
  layer_k<128><<<(M+63)/64, 512, 0, stream>>>(hb, nullptr, rowptr, pl1, eet + 1280,
      w1t + (size_t)256*136, w2t + (size_t)128*264, b1, 256, b2, 128, flag, ha, M);

  xstruct_k<<<(N+7)/8, 256, 0, stream>>>(ha, sgi, catb, M, N);

  bnstats1_k<256,true><<<256, 256, 0, stream>>>(catb, stats, N);
  bnfin_k<<<1, 256, 0, stream>>>(stats, g1, be1, flag, scl1, sft1, 256, 1.0f/N);

  // projection GEMM with folded BN1 on A and fused BN2 stats on output
  gemm_k<256,128,2,false,true,true><<<(N+63)/64, 256, 0, stream>>>(
      catb, wpt, bp, 0, flag, scl1, sft1, out2, stats + 512, N);

  bnfin_k<<<1, 128, 0, stream>>>(stats + 512, g2, be2, flag, scl2, sft2, 128, 1.0f/N);

  bn2apply_k<<<(N*32+255)/256, 256, 0, stream>>>(out2, scl2, sft2, flag, d_out, N);
}